// Round 10
// baseline (19.115 us; speedup 1.0000x reference)
//
#include <hip/hip_runtime.h>
#include <math.h>

// Problem constants (match reference)
constexpr int B = 4, S = 128, D = 256, TC = 1024;  // TC = D*4 (d,c flattened)
constexpr float EPS = 1e-6f;
constexpr int KS = 8, KW = 128;      // split-K for G (KS*KW = TC)
constexpr int ROWS = 8, TCOLS = 128; // kB tiling: 512 blocks -> 2 blocks/CU

// ws layout (floats): Wv[S][TC] | SWq[S*4] | SWk[S*4] | Gpart[KS][S][S]

// ---------------------------------------------------------------------------
// kA: 256 independent blocks, two roles (unchanged from R9 - validated).
// ---------------------------------------------------------------------------
__global__ __launch_bounds__(256)
void kA(const float* __restrict__ qw, const float* __restrict__ qb,
        const float* __restrict__ kw, const float* __restrict__ kb,
        const float* __restrict__ vw, const float* __restrict__ vb,
        float* __restrict__ Wv, float* __restrict__ SWq, float* __restrict__ SWk,
        float* __restrict__ Gpart)
{
    __shared__ __align__(16) float wkT[KW][S + 1];    // 66 KB exp'd K slice, transposed
    __shared__ __align__(16) float wqs[ROWS][KW + 4]; // exp'd Q tile, 16B-aligned rows
    __shared__ float ekb[KW], eqb[KW];
    __shared__ float redq[256], redk[256];

    const int blk = blockIdx.x, tid = threadIdx.x;

    if (blk < 128) {
        const int it = blk >> 3, ks = blk & 7;
        const int k0 = ks * KW, d0 = k0 >> 2, i0 = it * ROWS;

        // batch ALL global loads into registers (one latency window)
        float4 kv4[16];
        #pragma unroll
        for (int r = 0; r < 16; ++r) {
            int e = r * 256 + tid;                 // [4c][128j][8dd4]
            int dd4 = e & 7, j = (e >> 3) & 127, c = (e >> 10) & 3;
            kv4[r] = *(const float4*)&kw[(c * S + j) * D + d0 + dd4 * 4];
        }
        float4 q4;
        {
            int dd4 = tid & 7, i = (tid >> 3) & 7, c = tid >> 6;
            q4 = *(const float4*)&qw[(c * S + i0 + i) * D + d0 + dd4 * 4];
        }
        if (tid < KW) {
            ekb[tid] = __expf(kb[k0 + tid]);
            eqb[tid] = __expf(qb[k0 + tid]);
        }
        __syncthreads();   // ekb/eqb ready

        // exp + LDS store; kk = dd*4+c = dd4*16 + qd*4 + c
        #pragma unroll
        for (int r = 0; r < 16; ++r) {
            int e = r * 256 + tid;
            int dd4 = e & 7, j = (e >> 3) & 127, c = (e >> 10) & 3;
            int kkb = dd4 * 16 + c;
            wkT[kkb][j]      = __expf(kv4[r].x) + ekb[kkb];
            wkT[kkb + 4][j]  = __expf(kv4[r].y) + ekb[kkb + 4];
            wkT[kkb + 8][j]  = __expf(kv4[r].z) + ekb[kkb + 8];
            wkT[kkb + 12][j] = __expf(kv4[r].w) + ekb[kkb + 12];
        }
        {
            int dd4 = tid & 7, i = (tid >> 3) & 7, c = tid >> 6;
            int kkb = dd4 * 16 + c;
            wqs[i][kkb]      = __expf(q4.x) + eqb[kkb];
            wqs[i][kkb + 4]  = __expf(q4.y) + eqb[kkb + 4];
            wqs[i][kkb + 8]  = __expf(q4.z) + eqb[kkb + 8];
            wqs[i][kkb + 12] = __expf(q4.w) + eqb[kkb + 12];
        }
        __syncthreads();

        const int j = tid & 127, ih = tid >> 7;   // ih: 4-row half
        float acc[4] = {0.f, 0.f, 0.f, 0.f};
        for (int k = 0; k < KW; k += 4) {
            float kv0 = wkT[k][j], kv1 = wkT[k + 1][j];
            float kv2 = wkT[k + 2][j], kv3 = wkT[k + 3][j];
            #pragma unroll
            for (int r = 0; r < 4; ++r) {
                float4 q = *(const float4*)&wqs[ih * 4 + r][k];  // broadcast b128
                acc[r] += q.x * kv0 + q.y * kv1 + q.z * kv2 + q.w * kv3;
            }
        }
        #pragma unroll
        for (int r = 0; r < 4; ++r)
            Gpart[(size_t)(ks * S + i0 + ih * 4 + r) * S + j] = acc[r];
    } else {
        const int s = blk - 128;
        float pq = 0.f, pk = 0.f;
        #pragma unroll
        for (int r = 0; r < 4; ++r) {
            int t = r * 256 + tid;
            int c = t & 3, d = t >> 2;
            int wi = (c * S + s) * D + d;            // [4,S,D]
            pq += __expf(qw[wi]) + __expf(qb[t]);
            pk += __expf(kw[wi]) + __expf(kb[t]);
            Wv[s * TC + t] = __expf(vw[wi]) + __expf(vb[t]);
        }
        redq[tid] = pq; redk[tid] = pk;
        __syncthreads();
        if (tid < 4) {
            float sq = 0.f, sk = 0.f;
            for (int u = tid; u < 256; u += 4) { sq += redq[u]; sk += redk[u]; }
            SWq[s * 4 + tid] = sq; SWk[s * 4 + tid] = sk;
        }
    }
}

// ---------------------------------------------------------------------------
// kB: 512 blocks (2/CU), TCOLS=128. Fused scores + softmax + register PV.
//  scores: thread (si=tid>>5, sj4=(tid&31)*4): 8 independent Gpart float4s.
//  PV: thread (jg=tid>>5, cg=tid&31) owns j-set {m*8+jg} and cols cg*4..+3;
//  FMA from registers + 2-address LDS broadcasts; 8-way jg reduction in LDS.
// ---------------------------------------------------------------------------
__global__ __launch_bounds__(256)
void kB(const float* __restrict__ query, const float* __restrict__ key_in,
        const float* __restrict__ value,
        const float* __restrict__ Wv, const float* __restrict__ SWq,
        const float* __restrict__ SWk, const float* __restrict__ Gpart,
        float* __restrict__ out)
{
    __shared__ __align__(16) float att[ROWS][S];        // pre-softmax scores
    __shared__ __align__(16) float attT[S][ROWS];       // softmax'd, transposed
    __shared__ __align__(16) float red[8][ROWS][32][4]; // 32 KB jg-partials
    __shared__ __align__(16) float xkl[S][4], xvl[S][4], swkl[S][4];
    __shared__ float xql[ROWS][4], swql[ROWS][4];

    const int tt = blockIdx.x, i0 = blockIdx.y * ROWS, b = blockIdx.z;
    const int tid = threadIdx.x;
    const int w = tid >> 6;
    const int jg = tid >> 5, cg = tid & 31, c4 = cg * 4;

    for (int e = tid; e < S * 4; e += 256) {
        xkl[e >> 2][e & 3]  = fmaxf(key_in[b * S * 4 + e], EPS);
        xvl[e >> 2][e & 3]  = fmaxf(value[b * S * 4 + e], EPS);
        swkl[e >> 2][e & 3] = SWk[e];
    }
    if (tid < ROWS * 4) {
        xql[tid >> 2][tid & 3]  = fmaxf(query[(b * S + i0) * 4 + tid], EPS);
        swql[tid >> 2][tid & 3] = SWq[i0 * 4 + tid];
    }

    // scores: 8 independent float4 Gpart loads (ks ascending)
    const int si = tid >> 5, sj4 = (tid & 31) * 4;
    float4 g = make_float4(0.f, 0.f, 0.f, 0.f);
    #pragma unroll
    for (int ks = 0; ks < KS; ++ks) {
        float4 t = *(const float4*)&Gpart[(size_t)(ks * S + i0 + si) * S + sj4];
        g.x += t.x; g.y += t.y; g.z += t.z; g.w += t.w;
    }

    // prefetch PV first half: j = r*8 + jg
    float4 pf[8];
    #pragma unroll
    for (int r = 0; r < 8; ++r)
        pf[r] = *(const float4*)&Wv[(size_t)(r * 8 + jg) * TC + tt * TCOLS + c4];

    __syncthreads();   // xql/xkl/swkl ready
    {
        float sc[4] = {g.x, g.y, g.z, g.w};
        #pragma unroll
        for (int q = 0; q < 4; ++q) {
            int j = sj4 + q;
            #pragma unroll
            for (int c = 0; c < 4; ++c)
                sc[q] += (float)D * xql[si][c] * xkl[j][c]
                       + xql[si][c] * swkl[j][c] + swql[si][c] * xkl[j][c];
        }
        *(float4*)&att[si][sj4] = make_float4(sc[0], sc[1], sc[2], sc[3]);
    }
    __syncthreads();   // att complete

    // softmax over j per row; wave w handles rows w, w+4; write transposed
    {
        const int lane = tid & 63;
        #pragma unroll
        for (int rr = 0; rr < ROWS / 4; ++rr) {
            int i = w + rr * 4;
            float s0 = att[i][lane], s1 = att[i][lane + 64];
            float m = fmaxf(s0, s1);
            #pragma unroll
            for (int o = 32; o > 0; o >>= 1) m = fmaxf(m, __shfl_xor(m, o));
            float e0 = __expf(s0 - m), e1 = __expf(s1 - m);
            float sum = e0 + e1;
            #pragma unroll
            for (int o = 32; o > 0; o >>= 1) sum += __shfl_xor(sum, o);
            float inv = 1.f / sum;
            attT[lane][i]      = fmaxf(e0 * inv, EPS);   // _to_log(attn) clamp
            attT[lane + 64][i] = fmaxf(e1 * inv, EPS);
        }
    }
    __syncthreads();   // attT ready

    // PV: register-resident; 16 j per thread in 2 halves of 8
    float4 acc4[ROWS];
    #pragma unroll
    for (int i = 0; i < ROWS; ++i) acc4[i] = make_float4(0.f, 0.f, 0.f, 0.f);

    for (int half = 0; half < 2; ++half) {
        float4 pfn[8];
        if (half == 0) {
            #pragma unroll
            for (int r = 0; r < 8; ++r)
                pfn[r] = *(const float4*)&Wv[(size_t)((8 + r) * 8 + jg) * TC
                                             + tt * TCOLS + c4];
        }
        #pragma unroll
        for (int r = 0; r < 8; ++r) {
            int j = (half * 8 + r) * 8 + jg;
            float4 av0 = *(const float4*)&attT[j][0];    // 2 addrs/wave: free
            float4 av1 = *(const float4*)&attT[j][4];
            float4 xv  = *(const float4*)&xvl[j][0];
            float4 vv;
            vv.x = pf[r].x + xv.x; vv.y = pf[r].y + xv.y;
            vv.z = pf[r].z + xv.z; vv.w = pf[r].w + xv.w;
            float a8[8] = {av0.x, av0.y, av0.z, av0.w, av1.x, av1.y, av1.z, av1.w};
            #pragma unroll
            for (int i = 0; i < ROWS; ++i) {
                acc4[i].x += a8[i] * vv.x; acc4[i].y += a8[i] * vv.y;
                acc4[i].z += a8[i] * vv.z; acc4[i].w += a8[i] * vv.w;
            }
        }
        #pragma unroll
        for (int r = 0; r < 8; ++r) pf[r] = pfn[r];
    }

    // jg-reduction
    #pragma unroll
    for (int i = 0; i < ROWS; ++i)
        *(float4*)&red[jg][i][cg][0] = acc4[i];
    __syncthreads();

    const int col = tid & 127, rh = tid >> 7;
    float* ob = out + (size_t)(b * S + i0) * TC + tt * TCOLS + col;
    #pragma unroll
    for (int q = 0; q < 4; ++q) {
        int i = rh * 4 + q;
        float o = 0.f;
        #pragma unroll
        for (int g2 = 0; g2 < 8; ++g2)
            o += red[g2][i][col >> 2][col & 3];
        ob[i * TC] = o;
    }
}

extern "C" void kernel_launch(void* const* d_in, const int* in_sizes, int n_in,
                              void* d_out, int out_size, void* d_ws, size_t ws_size,
                              hipStream_t stream)
{
    const float* query  = (const float*)d_in[0];
    const float* key_in = (const float*)d_in[1];
    const float* value  = (const float*)d_in[2];
    const float* qw = (const float*)d_in[3];
    const float* qb = (const float*)d_in[4];
    const float* kw = (const float*)d_in[5];
    const float* kb = (const float*)d_in[6];
    const float* vw = (const float*)d_in[7];
    const float* vb = (const float*)d_in[8];
    float* out = (float*)d_out;

    float* Wv    = (float*)d_ws;
    float* SWq   = Wv + (size_t)S * TC;
    float* SWk   = SWq + S * 4;
    float* Gpart = SWk + S * 4;          // [KS][S][S] = 512 KB

    kA<<<256, 256, 0, stream>>>(qw, qb, kw, kb, vw, vb, Wv, SWq, SWk, Gpart);
    kB<<<dim3(TC / TCOLS, S / ROWS, B), 256, 0, stream>>>(
        query, key_in, value, Wv, SWq, SWk, Gpart, out);
}